// Round 1
// baseline (6691.650 us; speedup 1.0000x reference)
//
#include <hip/hip_runtime.h>
#include <hip/hip_bf16.h>
#include <cstddef>
#include <cstdint>

#define IN_F 4096
#define OUT_F 4096

// ---------------------------------------------------------------------------
// Stage 1: Cayley transform via Gauss-Jordan (no pivoting; I - skew has PD
// symmetric part so GJ is stable). Solves (I-S) X = (I+S); X = Q^T.
// Stores Qs[b][j][i] = Q[i][j] (i.e. X row-major) -- exactly the layout the
// factor GEMM wants for broadcast reads.
// ---------------------------------------------------------------------------
__global__ __launch_bounds__(256) void cayley_kernel(const float* __restrict__ R,
                                                     float* __restrict__ Qs) {
  __shared__ float Mm[64][65];
  __shared__ float Bm[64][65];
  const int b = blockIdx.x;                 // 0..191 (factor*64 + block)
  const float* Rb = R + (size_t)b * 4096;
  const int t = threadIdx.x;
  const int i = t >> 2;                     // row 0..63
  const int jb = (t & 3) << 4;              // 16-col chunk

  #pragma unroll 4
  for (int q = 0; q < 16; ++q) {
    int j = jb + q;
    float rij = Rb[i * 64 + j];
    float rji = Rb[j * 64 + i];
    float sk = 0.5f * (rij - rji);
    float id = (i == j) ? 1.0f : 0.0f;
    Mm[i][j] = id - sk;                     // I - skew
    Bm[i][j] = id + sk;                     // I + skew
  }
  __syncthreads();

  for (int k = 0; k < 64; ++k) {
    float inv = 1.0f / Mm[k][k];            // broadcast read (pre-scale value)
    float f = Mm[i][k];                     // row-i multiplier (untouched by scale)
    __syncthreads();
    if (t < 64) {                           // scale pivot row
      Mm[k][t] *= inv;
      Bm[k][t] *= inv;
    }
    __syncthreads();
    if (i != k) {
      #pragma unroll 4
      for (int q = 0; q < 16; ++q) {
        int j = jb + q;
        Mm[i][j] = fmaf(-f, Mm[k][j], Mm[i][j]);
        Bm[i][j] = fmaf(-f, Bm[k][j], Bm[i][j]);
      }
    }
    __syncthreads();
  }

  // Bm = (I-S)^{-1}(I+S) = Q^T ; flat copy out.
  float* out = Qs + (size_t)b * 4096;
  #pragma unroll 4
  for (int q = 0; q < 16; ++q) {
    int flat = t * 16 + q;
    out[flat] = Bm[flat >> 6][flat & 63];
  }
}

// ---------------------------------------------------------------------------
// Stage 2a: inverse perms. perm is [3][4096]; factor-0 inverse is not needed.
// ---------------------------------------------------------------------------
__global__ void invperm_kernel(const int* __restrict__ perm,
                               int* __restrict__ ip1, int* __restrict__ ip2) {
  int c = blockIdx.x * 256 + threadIdx.x;   // 0..4095
  ip1[perm[4096 + c]] = c;
  ip2[perm[8192 + c]] = c;
}

// Stage 2b: composed row-gather indices. rho1[k]=p0[ip1[k]], rho2[k]=p1[ip2[k]]
__global__ void compose_kernel(const int* __restrict__ perm,
                               const int* __restrict__ ip1,
                               const int* __restrict__ ip2,
                               int* __restrict__ rho1, int* __restrict__ rho2) {
  int k = blockIdx.x * 256 + threadIdx.x;
  rho1[k] = perm[ip1[k]];
  rho2[k] = perm[4096 + ip2[k]];
}

// ---------------------------------------------------------------------------
// Stage 3: transpose W with factor-0 scatter: U0[p0[c]][n] = W[n][c].
// After this, column perms become row perms (contiguous rows -> coalesced).
// ---------------------------------------------------------------------------
__global__ __launch_bounds__(256) void transpose_perm_kernel(const float* __restrict__ W,
                                                             const int* __restrict__ p0,
                                                             float* __restrict__ U0) {
  __shared__ float tile[64][65];
  const int c0 = blockIdx.x * 64;
  const int n0 = blockIdx.y * 64;
  const int t = threadIdx.x;
  const int r = t >> 2;
  const int cb = (t & 3) << 4;
  #pragma unroll
  for (int q = 0; q < 4; ++q) {
    float4 v = *(const float4*)(W + (size_t)(n0 + r) * IN_F + c0 + cb + q * 4);
    tile[r][cb + q * 4 + 0] = v.x;
    tile[r][cb + q * 4 + 1] = v.y;
    tile[r][cb + q * 4 + 2] = v.z;
    tile[r][cb + q * 4 + 3] = v.w;
  }
  __syncthreads();
  const int c = t >> 2;
  const int nb = (t & 3) << 4;
  const int dstrow = p0[c0 + c];
  #pragma unroll
  for (int q = 0; q < 4; ++q) {
    float4 v;
    v.x = tile[nb + q * 4 + 0][c];
    v.y = tile[nb + q * 4 + 1][c];
    v.z = tile[nb + q * 4 + 2][c];
    v.w = tile[nb + q * 4 + 3][c];
    *(float4*)(U0 + (size_t)dstrow * OUT_F + n0 + nb + q * 4) = v;
  }
}

// ---------------------------------------------------------------------------
// Stage 4: one butterfly factor in transposed space.
// dst[didx(g*64+i)][n] = scale(n) * sum_j Qt[g][j][i] * src[sidx(g*64+j)][n]
// Block: 256 thr = 4 waves; wave w owns i in [16w,16w+16), lane owns 4 n's.
// ---------------------------------------------------------------------------
__global__ __launch_bounds__(256) void factor_kernel(const float* __restrict__ src,
                                                     float* __restrict__ dst,
                                                     const float* __restrict__ Qt,
                                                     const int* __restrict__ rowIdx,
                                                     const int* __restrict__ dstIdx,
                                                     const float* __restrict__ s) {
  __shared__ float qt[64][64];      // [j][i]
  __shared__ int sidx[64];
  __shared__ int didx[64];
  const int g = blockIdx.y;
  const int n0 = blockIdx.x * 256;
  const int t = threadIdx.x;

  {
    const float* qg = Qt + (size_t)g * 4096;
    float4* qv = (float4*)&qt[0][0];
    #pragma unroll
    for (int q = 0; q < 4; ++q)
      qv[t * 4 + q] = *(const float4*)(qg + t * 16 + q * 4);
  }
  if (t < 64) {
    sidx[t] = rowIdx ? rowIdx[g * 64 + t] : g * 64 + t;
    didx[t] = dstIdx ? dstIdx[g * 64 + t] : g * 64 + t;
  }
  __syncthreads();

  const int w = t >> 6;
  const int lane = t & 63;
  const int nOff = n0 + lane * 4;
  float4 a[16];
  #pragma unroll
  for (int ii = 0; ii < 16; ++ii) a[ii] = make_float4(0.f, 0.f, 0.f, 0.f);

  for (int j = 0; j < 64; ++j) {
    float4 v = *(const float4*)(src + (size_t)sidx[j] * OUT_F + nOff);
    const float* qr = &qt[j][w * 16];
    #pragma unroll
    for (int ii = 0; ii < 16; ++ii) {
      float qq = qr[ii];
      a[ii].x = fmaf(qq, v.x, a[ii].x);
      a[ii].y = fmaf(qq, v.y, a[ii].y);
      a[ii].z = fmaf(qq, v.z, a[ii].z);
      a[ii].w = fmaf(qq, v.w, a[ii].w);
    }
  }

  float4 sv = make_float4(1.f, 1.f, 1.f, 1.f);
  if (s) sv = *(const float4*)(s + nOff);
  #pragma unroll
  for (int ii = 0; ii < 16; ++ii) {
    int r = didx[w * 16 + ii];
    float4 o;
    o.x = a[ii].x * sv.x; o.y = a[ii].y * sv.y;
    o.z = a[ii].z * sv.z; o.w = a[ii].w * sv.w;
    *(float4*)(dst + (size_t)r * OUT_F + nOff) = o;
  }
}

// ---------------------------------------------------------------------------
// Stage 5: main GEMM. C[m][n] = sum_k A[m][k] * B[k][n] + bias[n]
// A = x (row-major M x K), B = SWt (row-major K x N). fp32 vector-ALU,
// 128x128 tile, BK=32, 8x8 microtile per thread.
// ---------------------------------------------------------------------------
#define TM 128
#define TN 128
#define BKK 32

__global__ __launch_bounds__(256) void gemm_kernel(const float* __restrict__ A,
                                                   const float* __restrict__ B,
                                                   const float* __restrict__ bias,
                                                   float* __restrict__ C,
                                                   int M) {
  __shared__ float As[BKK][TM + 4];   // [k][m]
  __shared__ float Bs[BKK][TN + 4];   // [k][n]
  const int t = threadIdx.x;
  const int tx = t & 15;
  const int ty = t >> 4;
  const int m0 = blockIdx.y * TM;
  const int n0 = blockIdx.x * TN;
  const int K = IN_F;
  const int N = OUT_F;

  float acc[8][8];
  #pragma unroll
  for (int i2 = 0; i2 < 8; ++i2)
    #pragma unroll
    for (int j2 = 0; j2 < 8; ++j2) acc[i2][j2] = 0.f;

  const int arow = t >> 3;            // 0..31
  const int akc = (t & 7) << 2;       // 0,4,..,28
  const int brow = t >> 5;            // 0..7
  const int bn = (t & 31) << 2;       // 0,4,..,124

  for (int k0 = 0; k0 < K; k0 += BKK) {
    #pragma unroll
    for (int p = 0; p < 4; ++p) {
      int m = arow + p * 32;
      float4 v = *(const float4*)(A + (size_t)(m0 + m) * K + k0 + akc);
      As[akc + 0][m] = v.x;
      As[akc + 1][m] = v.y;
      As[akc + 2][m] = v.z;
      As[akc + 3][m] = v.w;
    }
    #pragma unroll
    for (int p = 0; p < 4; ++p) {
      int kk = brow + p * 8;
      float4 v = *(const float4*)(B + (size_t)(k0 + kk) * N + n0 + bn);
      *(float4*)&Bs[kk][bn] = v;
    }
    __syncthreads();
    #pragma unroll
    for (int kk = 0; kk < BKK; ++kk) {
      float av[8], bv[8];
      *(float4*)&av[0] = *(const float4*)&As[kk][ty * 8];
      *(float4*)&av[4] = *(const float4*)&As[kk][ty * 8 + 4];
      *(float4*)&bv[0] = *(const float4*)&Bs[kk][tx * 8];
      *(float4*)&bv[4] = *(const float4*)&Bs[kk][tx * 8 + 4];
      #pragma unroll
      for (int i2 = 0; i2 < 8; ++i2)
        #pragma unroll
        for (int j2 = 0; j2 < 8; ++j2)
          acc[i2][j2] = fmaf(av[i2], bv[j2], acc[i2][j2]);
    }
    __syncthreads();
  }

  float4 bv0 = *(const float4*)(bias + n0 + tx * 8);
  float4 bv1 = *(const float4*)(bias + n0 + tx * 8 + 4);
  #pragma unroll
  for (int i2 = 0; i2 < 8; ++i2) {
    int m = m0 + ty * 8 + i2;
    float4 o0, o1;
    o0.x = acc[i2][0] + bv0.x; o0.y = acc[i2][1] + bv0.y;
    o0.z = acc[i2][2] + bv0.z; o0.w = acc[i2][3] + bv0.w;
    o1.x = acc[i2][4] + bv1.x; o1.y = acc[i2][5] + bv1.y;
    o1.z = acc[i2][6] + bv1.z; o1.w = acc[i2][7] + bv1.w;
    *(float4*)(C + (size_t)m * N + n0 + tx * 8) = o0;
    *(float4*)(C + (size_t)m * N + n0 + tx * 8 + 4) = o1;
  }
}

// ---------------------------------------------------------------------------
extern "C" void kernel_launch(void* const* d_in, const int* in_sizes, int n_in,
                              void* d_out, int out_size, void* d_ws, size_t ws_size,
                              hipStream_t stream) {
  const float* x      = (const float*)d_in[0];
  const float* weight = (const float*)d_in[1];
  const float* bias   = (const float*)d_in[2];
  const float* boft_R = (const float*)d_in[3];
  const float* boft_s = (const float*)d_in[4];
  const int*   perm   = (const int*)d_in[5];
  float* out = (float*)d_out;

  // ws layout: Qs[3*64*4096] | bufA[4096*4096] | bufB[4096*4096] | 4 int idx arrays
  float* ws   = (float*)d_ws;
  float* Qs   = ws;                          // 786432 floats (3 MB)
  float* bufA = ws + 786432;                 // 64 MB
  float* bufB = bufA + 16777216;             // 64 MB
  int*   ints = (int*)(bufB + 16777216);
  int* ip1  = ints;
  int* ip2  = ints + 4096;
  int* rho1 = ints + 8192;
  int* rho2 = ints + 12288;

  const int M = in_sizes[0] / IN_F;          // 16384

  // 1. Cayley: Q^T per 64x64 block (192 blocks)
  hipLaunchKernelGGL(cayley_kernel, dim3(192), dim3(256), 0, stream, boft_R, Qs);
  // 2. perm inverses + compositions
  hipLaunchKernelGGL(invperm_kernel, dim3(16), dim3(256), 0, stream, perm, ip1, ip2);
  hipLaunchKernelGGL(compose_kernel, dim3(16), dim3(256), 0, stream, perm, ip1, ip2, rho1, rho2);
  // 3. W^T with factor-0 input perm folded in: bufA = U0
  hipLaunchKernelGGL(transpose_perm_kernel, dim3(64, 64), dim3(256), 0, stream,
                     weight, perm, bufA);
  // 4. three butterfly factors (block-diag GEMMs with folded row gathers)
  hipLaunchKernelGGL(factor_kernel, dim3(16, 64), dim3(256), 0, stream,
                     bufA, bufB, Qs, (const int*)nullptr, (const int*)nullptr,
                     (const float*)nullptr);
  hipLaunchKernelGGL(factor_kernel, dim3(16, 64), dim3(256), 0, stream,
                     bufB, bufA, Qs + 262144, rho1, (const int*)nullptr,
                     (const float*)nullptr);
  hipLaunchKernelGGL(factor_kernel, dim3(16, 64), dim3(256), 0, stream,
                     bufA, bufB, Qs + 524288, rho2, ip2, boft_s);
  // 5. out = x @ SWt + bias   (SWt = bufB, clean row-major [k][n])
  hipLaunchKernelGGL(gemm_kernel, dim3(OUT_F / TN, M / TM), dim3(256), 0, stream,
                     x, bufB, bias, out, M);
}

// Round 2
// 1453.393 us; speedup vs baseline: 4.6042x; 4.6042x over previous
//
#include <hip/hip_runtime.h>
#include <hip/hip_bf16.h>
#include <cstddef>
#include <cstdint>

#define IN_F 4096
#define OUT_F 4096

typedef __attribute__((ext_vector_type(8))) _Float16 half8;
typedef __attribute__((ext_vector_type(4))) float f32x4;

// ---------------------------------------------------------------------------
// Stage 1: Cayley transform via Gauss-Jordan (no pivoting; I - skew has PD
// symmetric part so GJ is stable). Solves (I-S) X = (I+S); X = Q^T.
// Stores Qs[b][j][i] = Q[i][j].
// ---------------------------------------------------------------------------
__global__ __launch_bounds__(256) void cayley_kernel(const float* __restrict__ R,
                                                     float* __restrict__ Qs) {
  __shared__ float Mm[64][65];
  __shared__ float Bm[64][65];
  const int b = blockIdx.x;                 // 0..191 (factor*64 + block)
  const float* Rb = R + (size_t)b * 4096;
  const int t = threadIdx.x;
  const int i = t >> 2;                     // row 0..63
  const int jb = (t & 3) << 4;              // 16-col chunk

  #pragma unroll 4
  for (int q = 0; q < 16; ++q) {
    int j = jb + q;
    float rij = Rb[i * 64 + j];
    float rji = Rb[j * 64 + i];
    float sk = 0.5f * (rij - rji);
    float id = (i == j) ? 1.0f : 0.0f;
    Mm[i][j] = id - sk;                     // I - skew
    Bm[i][j] = id + sk;                     // I + skew
  }
  __syncthreads();

  for (int k = 0; k < 64; ++k) {
    float inv = 1.0f / Mm[k][k];
    float f = Mm[i][k];
    __syncthreads();
    if (t < 64) {
      Mm[k][t] *= inv;
      Bm[k][t] *= inv;
    }
    __syncthreads();
    if (i != k) {
      #pragma unroll 4
      for (int q = 0; q < 16; ++q) {
        int j = jb + q;
        Mm[i][j] = fmaf(-f, Mm[k][j], Mm[i][j]);
        Bm[i][j] = fmaf(-f, Bm[k][j], Bm[i][j]);
      }
    }
    __syncthreads();
  }

  float* out = Qs + (size_t)b * 4096;
  #pragma unroll 4
  for (int q = 0; q < 16; ++q) {
    int flat = t * 16 + q;
    out[flat] = Bm[flat >> 6][flat & 63];
  }
}

// ---------------------------------------------------------------------------
__global__ void invperm_kernel(const int* __restrict__ perm,
                               int* __restrict__ ip1, int* __restrict__ ip2) {
  int c = blockIdx.x * 256 + threadIdx.x;   // 0..4095
  ip1[perm[4096 + c]] = c;
  ip2[perm[8192 + c]] = c;
}

__global__ void compose_kernel(const int* __restrict__ perm,
                               const int* __restrict__ ip1,
                               const int* __restrict__ ip2,
                               int* __restrict__ rho1, int* __restrict__ rho2) {
  int k = blockIdx.x * 256 + threadIdx.x;
  rho1[k] = perm[ip1[k]];
  rho2[k] = perm[4096 + ip2[k]];
}

// ---------------------------------------------------------------------------
// Stage 3: transpose W with factor-0 scatter: U0[p0[c]][n] = W[n][c].
// ---------------------------------------------------------------------------
__global__ __launch_bounds__(256) void transpose_perm_kernel(const float* __restrict__ W,
                                                             const int* __restrict__ p0,
                                                             float* __restrict__ U0) {
  __shared__ float tile[64][65];
  const int c0 = blockIdx.x * 64;
  const int n0 = blockIdx.y * 64;
  const int t = threadIdx.x;
  const int r = t >> 2;
  const int cb = (t & 3) << 4;
  #pragma unroll
  for (int q = 0; q < 4; ++q) {
    float4 v = *(const float4*)(W + (size_t)(n0 + r) * IN_F + c0 + cb + q * 4);
    tile[r][cb + q * 4 + 0] = v.x;
    tile[r][cb + q * 4 + 1] = v.y;
    tile[r][cb + q * 4 + 2] = v.z;
    tile[r][cb + q * 4 + 3] = v.w;
  }
  __syncthreads();
  const int c = t >> 2;
  const int nb = (t & 3) << 4;
  const int dstrow = p0[c0 + c];
  #pragma unroll
  for (int q = 0; q < 4; ++q) {
    float4 v;
    v.x = tile[nb + q * 4 + 0][c];
    v.y = tile[nb + q * 4 + 1][c];
    v.z = tile[nb + q * 4 + 2][c];
    v.w = tile[nb + q * 4 + 3][c];
    *(float4*)(U0 + (size_t)dstrow * OUT_F + n0 + nb + q * 4) = v;
  }
}

// ---------------------------------------------------------------------------
// Stage 4: one butterfly factor in transposed space.
// dst[didx(g*64+i)][n] = scale(n) * sum_j Qt[g][j][i] * src[sidx(g*64+j)][n]
// ---------------------------------------------------------------------------
__global__ __launch_bounds__(256) void factor_kernel(const float* __restrict__ src,
                                                     float* __restrict__ dst,
                                                     const float* __restrict__ Qt,
                                                     const int* __restrict__ rowIdx,
                                                     const int* __restrict__ dstIdx,
                                                     const float* __restrict__ s) {
  __shared__ float qt[64][64];      // [j][i]
  __shared__ int sidx[64];
  __shared__ int didx[64];
  const int g = blockIdx.y;
  const int n0 = blockIdx.x * 256;
  const int t = threadIdx.x;

  {
    const float* qg = Qt + (size_t)g * 4096;
    float4* qv = (float4*)&qt[0][0];
    #pragma unroll
    for (int q = 0; q < 4; ++q)
      qv[t * 4 + q] = *(const float4*)(qg + t * 16 + q * 4);
  }
  if (t < 64) {
    sidx[t] = rowIdx ? rowIdx[g * 64 + t] : g * 64 + t;
    didx[t] = dstIdx ? dstIdx[g * 64 + t] : g * 64 + t;
  }
  __syncthreads();

  const int w = t >> 6;
  const int lane = t & 63;
  const int nOff = n0 + lane * 4;
  float4 a[16];
  #pragma unroll
  for (int ii = 0; ii < 16; ++ii) a[ii] = make_float4(0.f, 0.f, 0.f, 0.f);

  for (int j = 0; j < 64; ++j) {
    float4 v = *(const float4*)(src + (size_t)sidx[j] * OUT_F + nOff);
    const float* qr = &qt[j][w * 16];
    #pragma unroll
    for (int ii = 0; ii < 16; ++ii) {
      float qq = qr[ii];
      a[ii].x = fmaf(qq, v.x, a[ii].x);
      a[ii].y = fmaf(qq, v.y, a[ii].y);
      a[ii].z = fmaf(qq, v.z, a[ii].z);
      a[ii].w = fmaf(qq, v.w, a[ii].w);
    }
  }

  float4 sv = make_float4(1.f, 1.f, 1.f, 1.f);
  if (s) sv = *(const float4*)(s + nOff);
  #pragma unroll
  for (int ii = 0; ii < 16; ++ii) {
    int r = didx[w * 16 + ii];
    float4 o;
    o.x = a[ii].x * sv.x; o.y = a[ii].y * sv.y;
    o.z = a[ii].z * sv.z; o.w = a[ii].w * sv.w;
    *(float4*)(dst + (size_t)r * OUT_F + nOff) = o;
  }
}

// ---------------------------------------------------------------------------
// Stage 5: transpose + convert: Bh[n][k] (fp16) = SWt[k][n] (fp32)
// ---------------------------------------------------------------------------
__global__ __launch_bounds__(256) void transpose_cvt_kernel(const float* __restrict__ S,
                                                            _Float16* __restrict__ D) {
  __shared__ float tile[64][65];
  const int k0 = blockIdx.x * 64;
  const int n0 = blockIdx.y * 64;
  const int t = threadIdx.x;
  const int r = t >> 2;              // k-row within tile
  const int cb = (t & 3) << 4;       // n-chunk
  #pragma unroll
  for (int q = 0; q < 4; ++q) {
    float4 v = *(const float4*)(S + (size_t)(k0 + r) * OUT_F + n0 + cb + q * 4);
    tile[r][cb + q * 4 + 0] = v.x;
    tile[r][cb + q * 4 + 1] = v.y;
    tile[r][cb + q * 4 + 2] = v.z;
    tile[r][cb + q * 4 + 3] = v.w;
  }
  __syncthreads();
  const int n = t >> 2;              // n-row within tile
  const int kb = (t & 3) << 4;       // k-chunk (16 halves)
  half8 h0, h1;
  #pragma unroll
  for (int q = 0; q < 8; ++q) {
    h0[q] = (_Float16)tile[kb + q][n];
    h1[q] = (_Float16)tile[kb + 8 + q][n];
  }
  _Float16* dp = D + (size_t)(n0 + n) * IN_F + k0 + kb;
  *(half8*)dp = h0;
  *(half8*)(dp + 8) = h1;
}

// ---------------------------------------------------------------------------
// Stage 6: MFMA GEMM. C[m][n] = sum_k A[m][k]*Bh[n][k] + bias[n]
// A fp32 (VGPR-staged + cvt to fp16 in LDS), B fp16 via global_load_lds.
// 128x128 tile, BK=32, 4 waves x (4x4) mfma_f32_16x16x32_f16.
// ---------------------------------------------------------------------------
#define GBM 128
#define GBN 128
#define GBK 32

__global__ __launch_bounds__(256) void mfma_gemm(const float* __restrict__ A,
                                                 const _Float16* __restrict__ Bh,
                                                 const float* __restrict__ bias,
                                                 float* __restrict__ C, int M) {
  __shared__ _Float16 Ash[GBM * GBK];  // [m][k], 8 KB
  __shared__ _Float16 Bsh[GBN * GBK];  // [n][k], 8 KB
  const int t = threadIdx.x;
  const int lane = t & 63;
  const int w = t >> 6;
  const int wr = w >> 1;              // wave row (0..1)
  const int wc = w & 1;               // wave col (0..1)
  const int m0 = blockIdx.y * GBM;
  const int n0 = blockIdx.x * GBN;
  const int K = IN_F;
  const int N = OUT_F;

  f32x4 acc[4][4];
  #pragma unroll
  for (int i = 0; i < 4; ++i)
    #pragma unroll
    for (int j = 0; j < 4; ++j) acc[i][j] = (f32x4){0.f, 0.f, 0.f, 0.f};

  // staging coords (same for A and B): round p covers rows [p*64, p*64+64)
  const int srow = t >> 2;            // 0..63
  const int skc = (t & 3) << 3;       // 0,8,16,24 (elements)

  // fragment LDS addresses (halves)
  const int frow = lane & 15;         // m/n within 16-tile
  const int fk = (lane >> 4) << 3;    // k offset 0/8/16/24

  for (int k0 = 0; k0 < K; k0 += GBK) {
    // --- B: async DMA global->LDS, 2 rounds of 256 lanes x 16B
    #pragma unroll
    for (int p = 0; p < 2; ++p) {
      const _Float16* gb = Bh + (size_t)(n0 + srow + p * 64) * K + k0 + skc;
      _Float16* lb = Bsh + ((size_t)(t & ~63) + p * 256) * 8;
      __builtin_amdgcn_global_load_lds(
          (const __attribute__((address_space(1))) uint32_t*)gb,
          (__attribute__((address_space(3))) uint32_t*)lb, 16, 0, 0);
    }
    // --- A: fp32 global -> VGPR -> cvt -> fp16 LDS (flat, conflict-free)
    #pragma unroll
    for (int p = 0; p < 2; ++p) {
      const float* ga = A + (size_t)(m0 + srow + p * 64) * K + k0 + skc;
      f32x4 v0 = *(const f32x4*)ga;
      f32x4 v1 = *(const f32x4*)(ga + 4);
      half8 h;
      h[0] = (_Float16)v0.x; h[1] = (_Float16)v0.y;
      h[2] = (_Float16)v0.z; h[3] = (_Float16)v0.w;
      h[4] = (_Float16)v1.x; h[5] = (_Float16)v1.y;
      h[6] = (_Float16)v1.z; h[7] = (_Float16)v1.w;
      *(half8*)(Ash + ((size_t)t + p * 256) * 8) = h;
    }
    __syncthreads();   // drains DMA (vmcnt) + ds_writes (lgkm)

    half8 af[4], bf[4];
    #pragma unroll
    for (int i = 0; i < 4; ++i)
      af[i] = *(const half8*)(Ash + (wr * 64 + i * 16 + frow) * GBK + fk);
    #pragma unroll
    for (int j = 0; j < 4; ++j)
      bf[j] = *(const half8*)(Bsh + (wc * 64 + j * 16 + frow) * GBK + fk);
    #pragma unroll
    for (int i = 0; i < 4; ++i)
      #pragma unroll
      for (int j = 0; j < 4; ++j)
        acc[i][j] = __builtin_amdgcn_mfma_f32_16x16x32_f16(af[i], bf[j], acc[i][j], 0, 0, 0);
    __syncthreads();   // all reads done before next overwrite
  }

  // epilogue: C/D layout col=lane&15, row=(lane>>4)*4+reg
  const int crow = (lane >> 4) << 2;
  const int ccol = lane & 15;
  #pragma unroll
  for (int j = 0; j < 4; ++j) {
    int n = n0 + wc * 64 + j * 16 + ccol;
    float bv = bias[n];
    #pragma unroll
    for (int i = 0; i < 4; ++i) {
      int mbase = m0 + wr * 64 + i * 16 + crow;
      #pragma unroll
      for (int r = 0; r < 4; ++r)
        C[(size_t)(mbase + r) * N + n] = acc[i][j][r] + bv;
    }
  }
}

// ---------------------------------------------------------------------------
extern "C" void kernel_launch(void* const* d_in, const int* in_sizes, int n_in,
                              void* d_out, int out_size, void* d_ws, size_t ws_size,
                              hipStream_t stream) {
  const float* x      = (const float*)d_in[0];
  const float* weight = (const float*)d_in[1];
  const float* bias   = (const float*)d_in[2];
  const float* boft_R = (const float*)d_in[3];
  const float* boft_s = (const float*)d_in[4];
  const int*   perm   = (const int*)d_in[5];
  float* out = (float*)d_out;

  // ws layout: Qs[3*64*4096] | bufA[4096*4096] | bufB[4096*4096] | idx arrays
  float* ws   = (float*)d_ws;
  float* Qs   = ws;                          // 3 MB
  float* bufA = ws + 786432;                 // 64 MB
  float* bufB = bufA + 16777216;             // 64 MB
  int*   ints = (int*)(bufB + 16777216);
  int* ip1  = ints;
  int* ip2  = ints + 4096;
  int* rho1 = ints + 8192;
  int* rho2 = ints + 12288;

  const int M = in_sizes[0] / IN_F;          // 16384

  // 1. Cayley: Q^T per 64x64 block (192 blocks)
  hipLaunchKernelGGL(cayley_kernel, dim3(192), dim3(256), 0, stream, boft_R, Qs);
  // 2. perm inverses + compositions
  hipLaunchKernelGGL(invperm_kernel, dim3(16), dim3(256), 0, stream, perm, ip1, ip2);
  hipLaunchKernelGGL(compose_kernel, dim3(16), dim3(256), 0, stream, perm, ip1, ip2, rho1, rho2);
  // 3. W^T with factor-0 input perm folded in: bufA = U0
  hipLaunchKernelGGL(transpose_perm_kernel, dim3(64, 64), dim3(256), 0, stream,
                     weight, perm, bufA);
  // 4. three butterfly factors (block-diag GEMMs with folded row gathers)
  hipLaunchKernelGGL(factor_kernel, dim3(16, 64), dim3(256), 0, stream,
                     bufA, bufB, Qs, (const int*)nullptr, (const int*)nullptr,
                     (const float*)nullptr);
  hipLaunchKernelGGL(factor_kernel, dim3(16, 64), dim3(256), 0, stream,
                     bufB, bufA, Qs + 262144, rho1, (const int*)nullptr,
                     (const float*)nullptr);
  hipLaunchKernelGGL(factor_kernel, dim3(16, 64), dim3(256), 0, stream,
                     bufA, bufB, Qs + 524288, rho2, ip2, boft_s);
  // 5. Bh[n][k] fp16 = transpose(SWt) ; bufA space reused as fp16 buffer
  _Float16* Bh = (_Float16*)bufA;
  hipLaunchKernelGGL(transpose_cvt_kernel, dim3(64, 64), dim3(256), 0, stream,
                     bufB, Bh);
  // 6. out = x @ Bh^T + bias (MFMA fp16)
  hipLaunchKernelGGL(mfma_gemm, dim3(OUT_F / GBN, M / GBM), dim3(256), 0, stream,
                     x, Bh, bias, out, M);
}